// Round 1
// baseline (305.646 us; speedup 1.0000x reference)
//
#include <hip/hip_runtime.h>

#define NPTS 8192
#define BN   16384          // B * N
#define D    32
#define R2   0.0009f        // float32(0.03**2) as the reference sees it
#define SIMT 0.7f
#define BLOCK 256
#define NBLK  (BN / BLOCK)  // 64
#define PFIELDS 34          // nbc, cnt, acc[32]

// ---------------------------------------------------------------------------
// pre: pack (x,y,z, leaf? sq : 1e30), inv-norm of embeddings, per-batch leaf cnt
// ---------------------------------------------------------------------------
__global__ __launch_bounds__(BLOCK) void pre_kernel(
    const float* __restrict__ pts, const float* __restrict__ emb,
    const int* __restrict__ leaf, float4* __restrict__ pts4,
    float* __restrict__ invn, int* __restrict__ leafcnt) {
  const int p = blockIdx.x * BLOCK + threadIdx.x;
  const float x = pts[3 * p + 0];
  const float y = pts[3 * p + 1];
  const float z = pts[3 * p + 2];
  const float sq = x * x + y * y + z * z;
  const int lf = leaf[p] > 0;
  float4 o;
  o.x = x; o.y = y; o.z = z;
  o.w = lf ? sq : 1e30f;   // sentinel: non-leaf j can never pass d2 < R2
  pts4[p] = o;

  const float4* er = (const float4*)(emb + (size_t)p * D);
  float ss = 0.f;
#pragma unroll
  for (int i = 0; i < D / 4; ++i) {
    float4 v = er[i];
    ss += v.x * v.x + v.y * v.y + v.z * v.z + v.w * v.w;
  }
  const float nrm = fmaxf(sqrtf(ss), 1e-8f);
  invn[p] = 1.0f / nrm;

  if (lf) atomicAdd(&leafcnt[p >> 13], 1);   // N = 8192 = 2^13
}

// ---------------------------------------------------------------------------
// pair scan: each lane owns point i; wave-uniform j sweep over its j-chunk.
// Writes SoA partials: part[(js*PFIELDS + f)*BN + p]
// ---------------------------------------------------------------------------
__global__ __launch_bounds__(BLOCK) void pair_kernel(
    const float4* __restrict__ pts4, const float* __restrict__ emb,
    const float* __restrict__ invn, float* __restrict__ part, int jlen) {
  const int p = blockIdx.x * BLOCK + threadIdx.x;
  const int b = blockIdx.x >> 5;   // 32 blocks of 256 per batch of 8192
  const float4* __restrict__ pjb = pts4 + (size_t)b * NPTS;
  const float*  __restrict__ ejb = emb  + (size_t)b * NPTS * D;
  const float*  __restrict__ inb = invn + (size_t)b * NPTS;

  const float4 pi = pts4[p];
  const float sq_i = pi.x * pi.x + pi.y * pi.y + pi.z * pi.z;
  const float inv_i = invn[p];

  float eni[D];
  {
    const float4* er = (const float4*)(emb + (size_t)p * D);
#pragma unroll
    for (int i = 0; i < D / 4; ++i) {
      float4 v = er[i];
      eni[4 * i + 0] = v.x * inv_i;
      eni[4 * i + 1] = v.y * inv_i;
      eni[4 * i + 2] = v.z * inv_i;
      eni[4 * i + 3] = v.w * inv_i;
    }
  }

  float acc[D];
#pragma unroll
  for (int d = 0; d < D; ++d) acc[d] = 0.f;
  float nbc = 0.f, cnt = 0.f;

  const int j0 = blockIdx.y * jlen;
  const int j1 = j0 + jlen;

  for (int j = j0; j < j1; j += 4) {
    float4 pj[4];
#pragma unroll
    for (int u = 0; u < 4; ++u) pj[u] = pjb[j + u];   // uniform -> s_load batch
#pragma unroll
    for (int u = 0; u < 4; ++u) {
      const float dot = pi.x * pj[u].x + pi.y * pj[u].y + pi.z * pj[u].z;
      const float d2 = sq_i + pj[u].w - 2.0f * dot;
      if (d2 < R2) {                       // rare: ~0.2% of pairs per lane
        nbc += 1.0f;
        const float* __restrict__ ej = ejb + (size_t)(j + u) * D;
        float s0 = 0.f, s1 = 0.f, s2 = 0.f, s3 = 0.f;
#pragma unroll
        for (int d = 0; d < D; d += 4) {
          s0 = fmaf(eni[d + 0], ej[d + 0], s0);
          s1 = fmaf(eni[d + 1], ej[d + 1], s1);
          s2 = fmaf(eni[d + 2], ej[d + 2], s2);
          s3 = fmaf(eni[d + 3], ej[d + 3], s3);
        }
        const float s = ((s0 + s1) + (s2 + s3)) * inb[j + u];
        if (s > SIMT) {
          cnt += 1.0f;
#pragma unroll
          for (int d = 0; d < D; ++d) acc[d] += ej[d];
        }
      }
    }
  }

  float* __restrict__ q = part + (size_t)blockIdx.y * PFIELDS * BN + p;
  q[0 * BN] = nbc;
  q[1 * BN] = cnt;
#pragma unroll
  for (int d = 0; d < D; ++d) q[(2 + d) * BN] = acc[d];
}

// ---------------------------------------------------------------------------
// reduce + MLP + select
// ---------------------------------------------------------------------------
__global__ __launch_bounds__(BLOCK) void reduce_kernel(
    const float* __restrict__ part, int jsplit,
    const float* __restrict__ emb, const int* __restrict__ leaf,
    const float* __restrict__ W1, const float* __restrict__ b1,
    const float* __restrict__ W2, const float* __restrict__ b2,
    const int* __restrict__ leafcnt, float* __restrict__ out) {
  const int p = blockIdx.x * BLOCK + threadIdx.x;
  const int b = blockIdx.x >> 5;

  float nbc = 0.f, cnt = 0.f;
  float acc[D];
#pragma unroll
  for (int d = 0; d < D; ++d) acc[d] = 0.f;
  for (int js = 0; js < jsplit; ++js) {
    const float* __restrict__ q = part + (size_t)js * PFIELDS * BN + p;
    nbc += q[0 * BN];
    cnt += q[1 * BN];
#pragma unroll
    for (int d = 0; d < D; ++d) acc[d] += q[(2 + d) * BN];
  }

  float e[D];
  {
    const float4* er = (const float4*)(emb + (size_t)p * D);
#pragma unroll
    for (int i = 0; i < D / 4; ++i) {
      float4 v = er[i];
      e[4 * i + 0] = v.x; e[4 * i + 1] = v.y;
      e[4 * i + 2] = v.z; e[4 * i + 3] = v.w;
    }
  }

  const float rinv = 1.0f / fmaxf(cnt, 1.0f);
  float mean[D];
#pragma unroll
  for (int d = 0; d < D; ++d) mean[d] = acc[d] * rinv;

  // h = relu([e, mean] @ W1 + b1);  W1 is (2D, D) row-major (in, out)
  float h[D];
#pragma unroll
  for (int k = 0; k < D; ++k) h[k] = b1[k];
  for (int d = 0; d < D; ++d) {
    const float c = e[d];
    const float* __restrict__ w = W1 + (size_t)d * D;
#pragma unroll
    for (int k = 0; k < D; ++k) h[k] = fmaf(c, w[k], h[k]);
  }
  for (int d = 0; d < D; ++d) {
    const float c = mean[d];
    const float* __restrict__ w = W1 + (size_t)(D + d) * D;
#pragma unroll
    for (int k = 0; k < D; ++k) h[k] = fmaf(c, w[k], h[k]);
  }
#pragma unroll
  for (int k = 0; k < D; ++k) h[k] = fmaxf(h[k], 0.f);

  float o[D];
#pragma unroll
  for (int m = 0; m < D; ++m) o[m] = b2[m];
  for (int k = 0; k < D; ++k) {
    const float c = h[k];
    const float* __restrict__ w = W2 + (size_t)k * D;
#pragma unroll
    for (int m = 0; m < D; ++m) o[m] = fmaf(c, w[m], o[m]);
  }

  const bool ok = leafcnt[b] >= 10;
  const bool cond = (leaf[p] > 0) && (nbc >= 2.0f) && (cnt >= 1.0f) && ok;

  float4* outr = (float4*)(out + (size_t)p * D);
#pragma unroll
  for (int i = 0; i < D / 4; ++i) {
    float4 v;
    if (cond) { v.x = o[4*i+0]; v.y = o[4*i+1]; v.z = o[4*i+2]; v.w = o[4*i+3]; }
    else      { v.x = e[4*i+0]; v.y = e[4*i+1]; v.z = e[4*i+2]; v.w = e[4*i+3]; }
    outr[i] = v;
  }
}

// ---------------------------------------------------------------------------
extern "C" void kernel_launch(void* const* d_in, const int* in_sizes, int n_in,
                              void* d_out, int out_size, void* d_ws, size_t ws_size,
                              hipStream_t stream) {
  (void)in_sizes; (void)n_in; (void)out_size;
  const float* pts  = (const float*)d_in[0];
  const float* emb  = (const float*)d_in[1];
  const int*   leaf = (const int*)d_in[2];
  const float* W1   = (const float*)d_in[3];
  const float* b1   = (const float*)d_in[4];
  const float* W2   = (const float*)d_in[5];
  const float* b2   = (const float*)d_in[6];
  float* out = (float*)d_out;

  char* ws = (char*)d_ws;
  float4* pts4   = (float4*)ws;                                   // 256 KB
  float*  invn   = (float*)(ws + (size_t)BN * 16);                // 64 KB
  int*    leafcnt= (int*)(ws + (size_t)BN * 16 + (size_t)BN * 4); // 16 B
  float*  part   = (float*)(ws + (size_t)BN * 16 + (size_t)BN * 4 + 256);
  const size_t fixed = (size_t)BN * 16 + (size_t)BN * 4 + 256;

  int jsplit = 1;
  if (fixed + (size_t)8 * PFIELDS * BN * 4 <= ws_size)      jsplit = 8;
  else if (fixed + (size_t)4 * PFIELDS * BN * 4 <= ws_size) jsplit = 4;
  else if (fixed + (size_t)2 * PFIELDS * BN * 4 <= ws_size) jsplit = 2;

  hipMemsetAsync(leafcnt, 0, 2 * sizeof(int), stream);
  pre_kernel<<<NBLK, BLOCK, 0, stream>>>(pts, emb, leaf, pts4, invn, leafcnt);
  pair_kernel<<<dim3(NBLK, jsplit), BLOCK, 0, stream>>>(pts4, emb, invn, part,
                                                        NPTS / jsplit);
  reduce_kernel<<<NBLK, BLOCK, 0, stream>>>(part, jsplit, emb, leaf, W1, b1, W2,
                                            b2, leafcnt, out);
}